// Round 4
// baseline (218.559 us; speedup 1.0000x reference)
//
#include <hip/hip_runtime.h>
#include <hip/hip_bf16.h>

#define DD   1024
#define HH   16
#define DHH  64
#define SS   2048
#define BB   2

using f32x4 = __attribute__((ext_vector_type(4))) float;
using s16x8 = __attribute__((ext_vector_type(8))) short;
using s16x4 = __attribute__((ext_vector_type(4))) short;
using u32x2 = __attribute__((ext_vector_type(2))) unsigned;

// round-to-nearest-even f32 -> bf16 bits
static __device__ __forceinline__ unsigned short f2bf(float x) {
    unsigned u = __float_as_uint(x);
    unsigned r = 0x7fffu + ((u >> 16) & 1u);
    return (unsigned short)((u + r) >> 16);
}
static __device__ __forceinline__ float bf2f(unsigned short h) {
    return __uint_as_float(((unsigned)h) << 16);
}

// async 16B global->LDS (linear dest: wave-uniform base + lane*16)
static __device__ __forceinline__ void glds16(const void* g, void* l) {
    __builtin_amdgcn_global_load_lds(
        (const __attribute__((address_space(1))) unsigned int*)g,
        (__attribute__((address_space(3))) unsigned int*)l, 16, 0, 0);
}

// byte offset in a [rows][64 bf16] (=128B/row) LDS tile, XOR-swizzled 16B blocks
static __device__ __forceinline__ int swz(int row, int blk) {
    return row * 128 + (((blk) ^ (row & 7)) << 4);
}

#define MFMA(a, b, c) __builtin_amdgcn_mfma_f32_16x16x32_bf16((a), (b), (c), 0, 0, 0)

// ws byte offsets
#define WTHI_OFF 0u
#define WTLO_OFF 6291456u      /* mats 0,1 only */
#define VT_OFF   6291456u      /* overlays Wtlo: live only after K2a is done */
#define QHI_OFF  14680064u
#define QLO_OFF  23068672u
#define KHI_OFF  31457280u
#define KLO_OFF  39845888u
/* total = 48234496 bytes */

// ---------------------------------------------------------------------------
// K1: split W into bf16 hi/lo and transpose to Wt[mat*16+h][e][d]
// ---------------------------------------------------------------------------
__global__ __launch_bounds__(256, 2) void wsplit_kernel(
    const float* __restrict__ Wq, const float* __restrict__ Wk, const float* __restrict__ Wv,
    short* __restrict__ Wthi, short* __restrict__ Wtlo)
{
    const int dt = blockIdx.x;        // d-tile (16)
    const int mh = blockIdx.y;        // mat*16+h (48)
    const int mat = mh >> 4, h = mh & 15;
    const int d0 = dt * 64;
    const float* Wm = (mat == 0 ? Wq : (mat == 1 ? Wk : Wv)) + (size_t)h * DD * DHH;

    __shared__ float Ws[64][65];
    const int t = threadIdx.x;

#pragma unroll
    for (int i = 0; i < 4; i++) {
        int f = t + 256 * i;
        int row = f >> 4;          // d-local
        int c4  = f & 15;          // e quad
        float4 v = *(const float4*)(Wm + (size_t)(d0 + row) * DHH + c4 * 4);
        Ws[row][c4 * 4 + 0] = v.x;
        Ws[row][c4 * 4 + 1] = v.y;
        Ws[row][c4 * 4 + 2] = v.z;
        Ws[row][c4 * 4 + 3] = v.w;
    }
    __syncthreads();

    const int e = t >> 2, dq = t & 3;
    s16x8 hi0, hi1, lo0, lo1;
#pragma unroll
    for (int i = 0; i < 8; i++) {
        float v = Ws[dq * 16 + i][e];
        unsigned short hb = f2bf(v);
        hi0[i] = (short)hb; lo0[i] = (short)f2bf(v - bf2f(hb));
    }
#pragma unroll
    for (int i = 0; i < 8; i++) {
        float v = Ws[dq * 16 + 8 + i][e];
        unsigned short hb = f2bf(v);
        hi1[i] = (short)hb; lo1[i] = (short)f2bf(v - bf2f(hb));
    }
    size_t off = ((size_t)(mh * 64 + e)) * DD + d0 + dq * 16;
    *(s16x8*)(Wthi + off)     = hi0;
    *(s16x8*)(Wthi + off + 8) = hi1;
    if (mat < 2) {
        *(s16x8*)(Wtlo + off)     = lo0;
        *(s16x8*)(Wtlo + off + 8) = lo1;
    }
}

// ---------------------------------------------------------------------------
// K2a: Q/K projection. A = Wt rows (n), B = X cols (s), 3-product split bf16.
// ---------------------------------------------------------------------------
__global__ __launch_bounds__(256, 2) void proj_qk_kernel(
    const float* __restrict__ X,
    const short* __restrict__ Wthi, const short* __restrict__ Wtlo,
    const float* __restrict__ bq, const float* __restrict__ bk,
    short* __restrict__ QhiG, short* __restrict__ QloG,
    short* __restrict__ KhiG, short* __restrict__ KloG)
{
    const int s0 = blockIdx.x * 128;
    const int n0 = blockIdx.y * 128;
    __shared__ __align__(16) char smem[65536];
    const int WHI = 0, WLO = 16384, XHI = 32768, XLO = 49152;

    const int t = threadIdx.x;
    const int w = t >> 6, lane = t & 63, g = lane >> 4, ln = lane & 15;
    const int wm = w >> 1, wn = w & 1;

    f32x4 acc[4][4];
#pragma unroll
    for (int i = 0; i < 4; i++)
#pragma unroll
        for (int j = 0; j < 4; j++) acc[i][j] = (f32x4){0.f, 0.f, 0.f, 0.f};

    for (int d0 = 0; d0 < DD; d0 += 64) {
        if (d0) __syncthreads();
#pragma unroll
        for (int p = 0; p < 4; p++) {
            int idx = p * 256 + t;
            int row = idx >> 3, blk = idx & 7;
            size_t so = (size_t)(n0 + row) * DD + d0 + ((blk ^ (row & 7)) * 8);
            glds16(Wthi + so, smem + WHI + idx * 16);
            glds16(Wtlo + so, smem + WLO + idx * 16);
        }
#pragma unroll
        for (int p = 0; p < 4; p++) {
            int idx = p * 256 + t;
            int row = idx >> 3, blk = idx & 7;
            const float* xp = X + (size_t)(s0 + row) * DD + d0 + blk * 8;
            float4 va = *(const float4*)xp;
            float4 vb = *(const float4*)(xp + 4);
            float v[8] = {va.x, va.y, va.z, va.w, vb.x, vb.y, vb.z, vb.w};
            s16x8 hi, lo;
#pragma unroll
            for (int i = 0; i < 8; i++) {
                unsigned short hb = f2bf(v[i]);
                hi[i] = (short)hb; lo[i] = (short)f2bf(v[i] - bf2f(hb));
            }
            *(s16x8*)(smem + XHI + swz(row, blk)) = hi;
            *(s16x8*)(smem + XLO + swz(row, blk)) = lo;
        }
        __syncthreads();

        s16x8 bxh[4][2], bxl[4][2];
#pragma unroll
        for (int nf = 0; nf < 4; nf++)
#pragma unroll
            for (int kst = 0; kst < 2; kst++) {
                int off = swz(64 * wn + nf * 16 + ln, kst * 4 + g);
                bxh[nf][kst] = *(const s16x8*)(smem + XHI + off);
                bxl[nf][kst] = *(const s16x8*)(smem + XLO + off);
            }
#pragma unroll
        for (int mf = 0; mf < 4; mf++) {
            s16x8 awh[2], awl[2];
#pragma unroll
            for (int kst = 0; kst < 2; kst++) {
                int off = swz(64 * wm + mf * 16 + ln, kst * 4 + g);
                awh[kst] = *(const s16x8*)(smem + WHI + off);
                awl[kst] = *(const s16x8*)(smem + WLO + off);
            }
#pragma unroll
            for (int kst = 0; kst < 2; kst++)
#pragma unroll
                for (int nf = 0; nf < 4; nf++) {
                    acc[mf][nf] = MFMA(awh[kst], bxh[nf][kst], acc[mf][nf]);
                    acc[mf][nf] = MFMA(awh[kst], bxl[nf][kst], acc[mf][nf]);
                    acc[mf][nf] = MFMA(awl[kst], bxh[nf][kst], acc[mf][nf]);
                }
        }
    }

    const int mat = n0 >> 10;                       // 0=Q, 1=K
    const int h = ((n0 + 64 * wm) >> 6) & 15;
    const float* bptr = (mat ? bk : bq) + h * 64;
    short* HiP = mat ? KhiG : QhiG;
    short* LoP = mat ? KloG : QloG;
    const float scale = mat ? 1.0f : 0.125f;

#pragma unroll
    for (int nf = 0; nf < 4; nf++) {
        int sg = s0 + 64 * wn + nf * 16 + ln;
        int bidx = sg >> 11, sr = sg & (SS - 1);
        size_t rowbase = ((size_t)((bidx * HH + h) * SS + sr)) * DHH;
#pragma unroll
        for (int mf = 0; mf < 4; mf++) {
            float4 bias = *(const float4*)(bptr + mf * 16 + g * 4);
            float bb[4] = {bias.x, bias.y, bias.z, bias.w};
            s16x4 hi4, lo4;
#pragma unroll
            for (int r = 0; r < 4; r++) {
                float vv = (acc[mf][nf][r] + bb[r]) * scale;
                unsigned short hb = f2bf(vv);
                hi4[r] = (short)hb; lo4[r] = (short)f2bf(vv - bf2f(hb));
            }
            size_t off = rowbase + mf * 16 + g * 4;
            *(s16x4*)(HiP + off) = hi4;
            *(s16x4*)(LoP + off) = lo4;
        }
    }
}

// ---------------------------------------------------------------------------
// K2b: V projection -> Vt[b,h,e,s] (transposed)
// ---------------------------------------------------------------------------
__global__ __launch_bounds__(256, 2) void proj_v_kernel(
    const float* __restrict__ X,
    const short* __restrict__ Wthi,
    const float* __restrict__ bv,
    short* __restrict__ VtG)
{
    const int s0 = blockIdx.x * 128;
    const int n0 = blockIdx.y * 128;     // within mat-2 block [0,1024)
    __shared__ __align__(16) char smem[32768];
    const int XHIo = 0, WHIo = 16384;

    const int t = threadIdx.x;
    const int w = t >> 6, lane = t & 63, g = lane >> 4, ln = lane & 15;
    const int wm = w >> 1, wn = w & 1;

    f32x4 acc[4][4];
#pragma unroll
    for (int i = 0; i < 4; i++)
#pragma unroll
        for (int j = 0; j < 4; j++) acc[i][j] = (f32x4){0.f, 0.f, 0.f, 0.f};

    for (int d0 = 0; d0 < DD; d0 += 64) {
        if (d0) __syncthreads();
#pragma unroll
        for (int p = 0; p < 4; p++) {
            int idx = p * 256 + t;
            int row = idx >> 3, blk = idx & 7;
            size_t so = (size_t)(2048 + n0 + row) * DD + d0 + ((blk ^ (row & 7)) * 8);
            glds16(Wthi + so, smem + WHIo + idx * 16);
        }
#pragma unroll
        for (int p = 0; p < 4; p++) {
            int idx = p * 256 + t;
            int row = idx >> 3, blk = idx & 7;
            const float* xp = X + (size_t)(s0 + row) * DD + d0 + blk * 8;
            float4 va = *(const float4*)xp;
            float4 vb = *(const float4*)(xp + 4);
            float v[8] = {va.x, va.y, va.z, va.w, vb.x, vb.y, vb.z, vb.w};
            s16x8 hi;
#pragma unroll
            for (int i = 0; i < 8; i++) hi[i] = (short)f2bf(v[i]);
            *(s16x8*)(smem + XHIo + swz(row, blk)) = hi;
        }
        __syncthreads();

        s16x8 bw[4][2];
#pragma unroll
        for (int nf = 0; nf < 4; nf++)
#pragma unroll
            for (int kst = 0; kst < 2; kst++)
                bw[nf][kst] = *(const s16x8*)(smem + WHIo + swz(64 * wn + nf * 16 + ln, kst * 4 + g));
#pragma unroll
        for (int mf = 0; mf < 4; mf++) {
            s16x8 ax[2];
#pragma unroll
            for (int kst = 0; kst < 2; kst++)
                ax[kst] = *(const s16x8*)(smem + XHIo + swz(64 * wm + mf * 16 + ln, kst * 4 + g));
#pragma unroll
            for (int kst = 0; kst < 2; kst++)
#pragma unroll
                for (int nf = 0; nf < 4; nf++)
                    acc[mf][nf] = MFMA(ax[kst], bw[nf][kst], acc[mf][nf]);
        }
    }

    const int h = ((n0 + 64 * wn) >> 6) & 15;
#pragma unroll
    for (int nf = 0; nf < 4; nf++) {
        int e = nf * 16 + ln;
        float bvv = bv[h * 64 + e];
#pragma unroll
        for (int mf = 0; mf < 4; mf++) {
            int sgb = s0 + 64 * wm + mf * 16 + g * 4;   // 4 consecutive s
            int bidx = sgb >> 11, sr = sgb & (SS - 1);
            s16x4 v4;
#pragma unroll
            for (int r = 0; r < 4; r++) v4[r] = (short)f2bf(acc[mf][nf][r] + bvv);
            *(s16x4*)(VtG + ((size_t)((bidx * HH + h) * DHH + e)) * SS + sr) = v4;
        }
    }
}

// ---------------------------------------------------------------------------
// K3: attention. 128 q-rows/block, 4 waves. Q frags direct from global (no Q
// LDS) -> 40KB LDS -> 4 blocks/CU. XCD-swizzled block mapping. cvt_pk P-pack,
// defer-max rescale, setprio around MFMA.
// ---------------------------------------------------------------------------
__global__ __launch_bounds__(256, 4) void attn_kernel(
    const short* __restrict__ QhiG, const short* __restrict__ QloG,
    const short* __restrict__ KhiG, const short* __restrict__ KloG,
    const short* __restrict__ VtG,
    float* __restrict__ out)
{
    // XCD-aware bijective swizzle: 512 blocks, 8 XCDs, 64 wids/XCD ->
    // 4 consecutive (h,b) groups per XCD (K/V working set ~3MB < 4MB L2).
    const int wid = (blockIdx.x & 7) * 64 + (blockIdx.x >> 3);
    const int qt = wid & 15, h = (wid >> 4) & 15, b = wid >> 8;
    const int q0 = qt * 128;
    const size_t ho = (size_t)(b * HH + h) * SS * DHH;   // same stride for Vt

    __shared__ __align__(16) char smem[40960];
    const int KHI = 0, KLO = 8192, VT = 16384, PS = 24576;

    const int t = threadIdx.x;
    const int w = t >> 6, lane = t & 63, g = lane >> 4, ln = lane & 15;

    // Q fragments straight from global (read once)
    s16x8 qh[2][2], ql[2][2];
#pragma unroll
    for (int nf = 0; nf < 2; nf++)
#pragma unroll
        for (int kst = 0; kst < 2; kst++) {
            size_t off = ho + (size_t)(q0 + 32 * w + nf * 16 + ln) * DHH + kst * 32 + g * 8;
            qh[nf][kst] = *(const s16x8*)(QhiG + off);
            ql[nf][kst] = *(const s16x8*)(QloG + off);
        }

    f32x4 o[4][2];
#pragma unroll
    for (int i = 0; i < 4; i++)
#pragma unroll
        for (int j = 0; j < 2; j++) o[i][j] = (f32x4){0.f, 0.f, 0.f, 0.f};
    float m[2] = {-3.0e38f, -3.0e38f}, l[2] = {0.f, 0.f};

    for (int kt = 0; kt < SS / 64; kt++) {
        const int k0 = kt * 64;
        const bool do_pv = (kt <= 2 * qt + 1);
        __syncthreads();   // previous tile's reads of K/V done
#pragma unroll
        for (int p = 0; p < 2; p++) {
            int idx = p * 256 + t;
            int row = idx >> 3, blk = idx & 7;
            int soff = (blk ^ (row & 7)) * 8;
            glds16(KhiG + ho + (size_t)(k0 + row) * DHH + soff, smem + KHI + idx * 16);
            glds16(KloG + ho + (size_t)(k0 + row) * DHH + soff, smem + KLO + idx * 16);
            if (do_pv)
                glds16(VtG + ho + (size_t)row * SS + k0 + soff, smem + VT + idx * 16);
        }
        __syncthreads();

        // S^T tile: rows = k (64), cols = q (32 per wave)
        f32x4 s[4][2];
#pragma unroll
        for (int i = 0; i < 4; i++)
#pragma unroll
            for (int j = 0; j < 2; j++) s[i][j] = (f32x4){0.f, 0.f, 0.f, 0.f};

        __builtin_amdgcn_s_setprio(1);
#pragma unroll
        for (int kst = 0; kst < 2; kst++) {
            s16x8 akh[4], akl[4];
#pragma unroll
            for (int mf = 0; mf < 4; mf++) {
                int off = swz(mf * 16 + ln, kst * 4 + g);
                akh[mf] = *(const s16x8*)(smem + KHI + off);
                akl[mf] = *(const s16x8*)(smem + KLO + off);
            }
#pragma unroll
            for (int mf = 0; mf < 4; mf++)
#pragma unroll
                for (int nf = 0; nf < 2; nf++) {
                    s[mf][nf] = MFMA(akh[mf], qh[nf][kst], s[mf][nf]);
                    s[mf][nf] = MFMA(akh[mf], ql[nf][kst], s[mf][nf]);
                    s[mf][nf] = MFMA(akl[mf], qh[nf][kst], s[mf][nf]);
                }
        }
        __builtin_amdgcn_s_setprio(0);

        // online softmax over FULL row (reference masks AFTER softmax).
        // defer-max (T13): skip O/l rescale when tile max grows <= 8.
#pragma unroll
        for (int nf = 0; nf < 2; nf++) {
            float pm = s[0][nf][0];
#pragma unroll
            for (int mf = 0; mf < 4; mf++)
#pragma unroll
                for (int r = 0; r < 4; r++) pm = fmaxf(pm, s[mf][nf][r]);
            pm = fmaxf(pm, __shfl_xor(pm, 16));
            pm = fmaxf(pm, __shfl_xor(pm, 32));
            const bool defer = __all(pm - m[nf] <= 8.0f);
            float nm = defer ? m[nf] : fmaxf(m[nf], pm);
            float ps = 0.f;
#pragma unroll
            for (int mf = 0; mf < 4; mf++)
#pragma unroll
                for (int r = 0; r < 4; r++) {
                    float pe = __expf(s[mf][nf][r] - nm);
                    s[mf][nf][r] = pe;
                    ps += pe;
                }
            ps += __shfl_xor(ps, 16);
            ps += __shfl_xor(ps, 32);
            if (defer) {
                l[nf] += ps;
            } else {
                float fac = __expf(m[nf] - nm);
                l[nf] = l[nf] * fac + ps;
                m[nf] = nm;
#pragma unroll
                for (int mf = 0; mf < 4; mf++)
#pragma unroll
                    for (int r = 0; r < 4; r++) o[mf][nf][r] *= fac;
            }
        }

        if (do_pv) {
            // write masked P^T (bf16) to LDS via v_cvt_pk_bf16_f32
#pragma unroll
            for (int nf = 0; nf < 2; nf++) {
                int qrow = 32 * w + nf * 16 + ln;
                int qg = q0 + qrow;
#pragma unroll
                for (int mf = 0; mf < 4; mf++) {
                    int kb = k0 + mf * 16 + g * 4;
                    float p0 = (kb + 0 > qg) ? 0.f : s[mf][nf][0];
                    float p1 = (kb + 1 > qg) ? 0.f : s[mf][nf][1];
                    float p2 = (kb + 2 > qg) ? 0.f : s[mf][nf][2];
                    float p3 = (kb + 3 > qg) ? 0.f : s[mf][nf][3];
                    unsigned lo_, hi_;
                    asm("v_cvt_pk_bf16_f32 %0, %1, %2" : "=v"(lo_) : "v"(p0), "v"(p1));
                    asm("v_cvt_pk_bf16_f32 %0, %1, %2" : "=v"(hi_) : "v"(p2), "v"(p3));
                    u32x2 pk; pk.x = lo_; pk.y = hi_;
                    int byte = PS + qrow * 128 + ((((mf * 2 + (g >> 1)) ^ (qrow & 7))) << 4) + (g & 1) * 8;
                    *(u32x2*)(smem + byte) = pk;
                }
            }
            asm volatile("s_waitcnt lgkmcnt(0)" ::: "memory");
            __builtin_amdgcn_sched_barrier(0);
            __builtin_amdgcn_s_setprio(1);
#pragma unroll
            for (int kst = 0; kst < 2; kst++) {
                s16x8 av[4], bp[2];
#pragma unroll
                for (int mf = 0; mf < 4; mf++)
                    av[mf] = *(const s16x8*)(smem + VT + swz(mf * 16 + ln, kst * 4 + g));
#pragma unroll
                for (int nf = 0; nf < 2; nf++)
                    bp[nf] = *(const s16x8*)(smem + PS + swz(32 * w + nf * 16 + ln, kst * 4 + g));
#pragma unroll
                for (int mf = 0; mf < 4; mf++)
#pragma unroll
                    for (int nf = 0; nf < 2; nf++)
                        o[mf][nf] = MFMA(av[mf], bp[nf], o[mf][nf]);
            }
            __builtin_amdgcn_s_setprio(0);
        }
    }

    // epilogue: Z^T rows = e, cols = q -> out[b][q][h*64+e]
#pragma unroll
    for (int nf = 0; nf < 2; nf++) {
        float inv = 1.0f / l[nf];
        int qg = q0 + 32 * w + nf * 16 + ln;
        float* op = out + ((size_t)(b * SS + qg)) * (HH * DHH) + h * DHH;
#pragma unroll
        for (int mf = 0; mf < 4; mf++) {
            float4 vv = {o[mf][nf][0] * inv, o[mf][nf][1] * inv,
                         o[mf][nf][2] * inv, o[mf][nf][3] * inv};
            *(float4*)(op + mf * 16 + g * 4) = vv;
        }
    }
}

extern "C" void kernel_launch(void* const* d_in, const int* in_sizes, int n_in,
                              void* d_out, int out_size, void* d_ws, size_t ws_size,
                              hipStream_t stream) {
    const float* X  = (const float*)d_in[0];
    const float* Wq = (const float*)d_in[1];
    const float* Wk = (const float*)d_in[2];
    const float* Wv = (const float*)d_in[3];
    const float* bq = (const float*)d_in[4];
    const float* bk = (const float*)d_in[5];
    const float* bv = (const float*)d_in[6];
    float* out = (float*)d_out;

    char* wsb = (char*)d_ws;
    short* Wthi = (short*)(wsb + WTHI_OFF);
    short* Wtlo = (short*)(wsb + WTLO_OFF);
    short* Vt   = (short*)(wsb + VT_OFF);     // overlays Wtlo (sequential lifetime)
    short* Qhi  = (short*)(wsb + QHI_OFF);
    short* Qlo  = (short*)(wsb + QLO_OFF);
    short* Khi  = (short*)(wsb + KHI_OFF);
    short* Klo  = (short*)(wsb + KLO_OFF);

    wsplit_kernel<<<dim3(16, 48), 256, 0, stream>>>(Wq, Wk, Wv, Wthi, Wtlo);
    proj_qk_kernel<<<dim3(32, 16), 256, 0, stream>>>(X, Wthi, Wtlo, bq, bk,
                                                     Qhi, Qlo, Khi, Klo);
    proj_v_kernel<<<dim3(32, 8), 256, 0, stream>>>(X, Wthi, bv, Vt);
    attn_kernel<<<512, 256, 0, stream>>>(Qhi, Qlo, Khi, Klo, Vt, out);
}

// Round 5
// 189.148 us; speedup vs baseline: 1.1555x; 1.1555x over previous
//
#include <hip/hip_runtime.h>
#include <hip/hip_bf16.h>

#define DD   1024
#define HH   16
#define DHH  64
#define SS   2048
#define BB   2

using f32x4 = __attribute__((ext_vector_type(4))) float;
using s16x8 = __attribute__((ext_vector_type(8))) short;
using s16x4 = __attribute__((ext_vector_type(4))) short;

// round-to-nearest-even f32 -> bf16 bits
static __device__ __forceinline__ unsigned short f2bf(float x) {
    unsigned u = __float_as_uint(x);
    unsigned r = 0x7fffu + ((u >> 16) & 1u);
    return (unsigned short)((u + r) >> 16);
}
static __device__ __forceinline__ float bf2f(unsigned short h) {
    return __uint_as_float(((unsigned)h) << 16);
}

// async 16B global->LDS (linear dest: wave-uniform base + lane*16)
static __device__ __forceinline__ void glds16(const void* g, void* l) {
    __builtin_amdgcn_global_load_lds(
        (const __attribute__((address_space(1))) unsigned int*)g,
        (__attribute__((address_space(3))) unsigned int*)l, 16, 0, 0);
}

// byte offset in a [rows][64 bf16] (=128B/row) LDS tile, XOR-swizzled 16B blocks
static __device__ __forceinline__ int swz(int row, int blk) {
    return row * 128 + (((blk) ^ (row & 7)) << 4);
}

#define MFMA(a, b, c) __builtin_amdgcn_mfma_f32_16x16x32_bf16((a), (b), (c), 0, 0, 0)

// ws byte offsets
#define WTHI_OFF 0u
#define WTLO_OFF 6291456u      /* mats 0,1 only */
#define VT_OFF   6291456u      /* overlays Wtlo: live only after K2a is done */
#define QHI_OFF  14680064u
#define QLO_OFF  23068672u
#define KHI_OFF  31457280u
#define KLO_OFF  39845888u
/* total = 48234496 bytes */

// ---------------------------------------------------------------------------
// K1: split W into bf16 hi/lo and transpose to Wt[mat*16+h][e][d]
// ---------------------------------------------------------------------------
__global__ __launch_bounds__(256, 2) void wsplit_kernel(
    const float* __restrict__ Wq, const float* __restrict__ Wk, const float* __restrict__ Wv,
    short* __restrict__ Wthi, short* __restrict__ Wtlo)
{
    const int dt = blockIdx.x;        // d-tile (16)
    const int mh = blockIdx.y;        // mat*16+h (48)
    const int mat = mh >> 4, h = mh & 15;
    const int d0 = dt * 64;
    const float* Wm = (mat == 0 ? Wq : (mat == 1 ? Wk : Wv)) + (size_t)h * DD * DHH;

    __shared__ float Ws[64][65];
    const int t = threadIdx.x;

#pragma unroll
    for (int i = 0; i < 4; i++) {
        int f = t + 256 * i;
        int row = f >> 4;          // d-local
        int c4  = f & 15;          // e quad
        float4 v = *(const float4*)(Wm + (size_t)(d0 + row) * DHH + c4 * 4);
        Ws[row][c4 * 4 + 0] = v.x;
        Ws[row][c4 * 4 + 1] = v.y;
        Ws[row][c4 * 4 + 2] = v.z;
        Ws[row][c4 * 4 + 3] = v.w;
    }
    __syncthreads();

    const int e = t >> 2, dq = t & 3;
    s16x8 hi0, hi1, lo0, lo1;
#pragma unroll
    for (int i = 0; i < 8; i++) {
        float v = Ws[dq * 16 + i][e];
        unsigned short hb = f2bf(v);
        hi0[i] = (short)hb; lo0[i] = (short)f2bf(v - bf2f(hb));
    }
#pragma unroll
    for (int i = 0; i < 8; i++) {
        float v = Ws[dq * 16 + 8 + i][e];
        unsigned short hb = f2bf(v);
        hi1[i] = (short)hb; lo1[i] = (short)f2bf(v - bf2f(hb));
    }
    size_t off = ((size_t)(mh * 64 + e)) * DD + d0 + dq * 16;
    *(s16x8*)(Wthi + off)     = hi0;
    *(s16x8*)(Wthi + off + 8) = hi1;
    if (mat < 2) {
        *(s16x8*)(Wtlo + off)     = lo0;
        *(s16x8*)(Wtlo + off + 8) = lo1;
    }
}

// ---------------------------------------------------------------------------
// K2a: Q/K projection. A = Wt rows (n), B = X cols (s), 3-product split bf16.
// ---------------------------------------------------------------------------
__global__ __launch_bounds__(256, 2) void proj_qk_kernel(
    const float* __restrict__ X,
    const short* __restrict__ Wthi, const short* __restrict__ Wtlo,
    const float* __restrict__ bq, const float* __restrict__ bk,
    short* __restrict__ QhiG, short* __restrict__ QloG,
    short* __restrict__ KhiG, short* __restrict__ KloG)
{
    const int s0 = blockIdx.x * 128;
    const int n0 = blockIdx.y * 128;
    __shared__ __align__(16) char smem[65536];
    const int WHI = 0, WLO = 16384, XHI = 32768, XLO = 49152;

    const int t = threadIdx.x;
    const int w = t >> 6, lane = t & 63, g = lane >> 4, ln = lane & 15;
    const int wm = w >> 1, wn = w & 1;

    f32x4 acc[4][4];
#pragma unroll
    for (int i = 0; i < 4; i++)
#pragma unroll
        for (int j = 0; j < 4; j++) acc[i][j] = (f32x4){0.f, 0.f, 0.f, 0.f};

    for (int d0 = 0; d0 < DD; d0 += 64) {
        if (d0) __syncthreads();
#pragma unroll
        for (int p = 0; p < 4; p++) {
            int idx = p * 256 + t;
            int row = idx >> 3, blk = idx & 7;
            size_t so = (size_t)(n0 + row) * DD + d0 + ((blk ^ (row & 7)) * 8);
            glds16(Wthi + so, smem + WHI + idx * 16);
            glds16(Wtlo + so, smem + WLO + idx * 16);
        }
#pragma unroll
        for (int p = 0; p < 4; p++) {
            int idx = p * 256 + t;
            int row = idx >> 3, blk = idx & 7;
            const float* xp = X + (size_t)(s0 + row) * DD + d0 + blk * 8;
            float4 va = *(const float4*)xp;
            float4 vb = *(const float4*)(xp + 4);
            float v[8] = {va.x, va.y, va.z, va.w, vb.x, vb.y, vb.z, vb.w};
            s16x8 hi, lo;
#pragma unroll
            for (int i = 0; i < 8; i++) {
                unsigned short hb = f2bf(v[i]);
                hi[i] = (short)hb; lo[i] = (short)f2bf(v[i] - bf2f(hb));
            }
            *(s16x8*)(smem + XHI + swz(row, blk)) = hi;
            *(s16x8*)(smem + XLO + swz(row, blk)) = lo;
        }
        __syncthreads();

        s16x8 bxh[4][2], bxl[4][2];
#pragma unroll
        for (int nf = 0; nf < 4; nf++)
#pragma unroll
            for (int kst = 0; kst < 2; kst++) {
                int off = swz(64 * wn + nf * 16 + ln, kst * 4 + g);
                bxh[nf][kst] = *(const s16x8*)(smem + XHI + off);
                bxl[nf][kst] = *(const s16x8*)(smem + XLO + off);
            }
#pragma unroll
        for (int mf = 0; mf < 4; mf++) {
            s16x8 awh[2], awl[2];
#pragma unroll
            for (int kst = 0; kst < 2; kst++) {
                int off = swz(64 * wm + mf * 16 + ln, kst * 4 + g);
                awh[kst] = *(const s16x8*)(smem + WHI + off);
                awl[kst] = *(const s16x8*)(smem + WLO + off);
            }
#pragma unroll
            for (int kst = 0; kst < 2; kst++)
#pragma unroll
                for (int nf = 0; nf < 4; nf++) {
                    acc[mf][nf] = MFMA(awh[kst], bxh[nf][kst], acc[mf][nf]);
                    acc[mf][nf] = MFMA(awh[kst], bxl[nf][kst], acc[mf][nf]);
                    acc[mf][nf] = MFMA(awl[kst], bxh[nf][kst], acc[mf][nf]);
                }
        }
    }

    const int mat = n0 >> 10;                       // 0=Q, 1=K
    const int h = ((n0 + 64 * wm) >> 6) & 15;
    const float* bptr = (mat ? bk : bq) + h * 64;
    short* HiP = mat ? KhiG : QhiG;
    short* LoP = mat ? KloG : QloG;
    const float scale = mat ? 1.0f : 0.125f;

#pragma unroll
    for (int nf = 0; nf < 4; nf++) {
        int sg = s0 + 64 * wn + nf * 16 + ln;
        int bidx = sg >> 11, sr = sg & (SS - 1);
        size_t rowbase = ((size_t)((bidx * HH + h) * SS + sr)) * DHH;
#pragma unroll
        for (int mf = 0; mf < 4; mf++) {
            float4 bias = *(const float4*)(bptr + mf * 16 + g * 4);
            float bb[4] = {bias.x, bias.y, bias.z, bias.w};
            s16x4 hi4, lo4;
#pragma unroll
            for (int r = 0; r < 4; r++) {
                float vv = (acc[mf][nf][r] + bb[r]) * scale;
                unsigned short hb = f2bf(vv);
                hi4[r] = (short)hb; lo4[r] = (short)f2bf(vv - bf2f(hb));
            }
            size_t off = rowbase + mf * 16 + g * 4;
            *(s16x4*)(HiP + off) = hi4;
            *(s16x4*)(LoP + off) = lo4;
        }
    }
}

// ---------------------------------------------------------------------------
// K2b: V projection -> Vt[b,h,e,s] (transposed)
// ---------------------------------------------------------------------------
__global__ __launch_bounds__(256, 2) void proj_v_kernel(
    const float* __restrict__ X,
    const short* __restrict__ Wthi,
    const float* __restrict__ bv,
    short* __restrict__ VtG)
{
    const int s0 = blockIdx.x * 128;
    const int n0 = blockIdx.y * 128;     // within mat-2 block [0,1024)
    __shared__ __align__(16) char smem[32768];
    const int XHIo = 0, WHIo = 16384;

    const int t = threadIdx.x;
    const int w = t >> 6, lane = t & 63, g = lane >> 4, ln = lane & 15;
    const int wm = w >> 1, wn = w & 1;

    f32x4 acc[4][4];
#pragma unroll
    for (int i = 0; i < 4; i++)
#pragma unroll
        for (int j = 0; j < 4; j++) acc[i][j] = (f32x4){0.f, 0.f, 0.f, 0.f};

    for (int d0 = 0; d0 < DD; d0 += 64) {
        if (d0) __syncthreads();
#pragma unroll
        for (int p = 0; p < 4; p++) {
            int idx = p * 256 + t;
            int row = idx >> 3, blk = idx & 7;
            size_t so = (size_t)(2048 + n0 + row) * DD + d0 + ((blk ^ (row & 7)) * 8);
            glds16(Wthi + so, smem + WHIo + idx * 16);
        }
#pragma unroll
        for (int p = 0; p < 4; p++) {
            int idx = p * 256 + t;
            int row = idx >> 3, blk = idx & 7;
            const float* xp = X + (size_t)(s0 + row) * DD + d0 + blk * 8;
            float4 va = *(const float4*)xp;
            float4 vb = *(const float4*)(xp + 4);
            float v[8] = {va.x, va.y, va.z, va.w, vb.x, vb.y, vb.z, vb.w};
            s16x8 hi;
#pragma unroll
            for (int i = 0; i < 8; i++) hi[i] = (short)f2bf(v[i]);
            *(s16x8*)(smem + XHIo + swz(row, blk)) = hi;
        }
        __syncthreads();

        s16x8 bw[4][2];
#pragma unroll
        for (int nf = 0; nf < 4; nf++)
#pragma unroll
            for (int kst = 0; kst < 2; kst++)
                bw[nf][kst] = *(const s16x8*)(smem + WHIo + swz(64 * wn + nf * 16 + ln, kst * 4 + g));
#pragma unroll
        for (int mf = 0; mf < 4; mf++) {
            s16x8 ax[2];
#pragma unroll
            for (int kst = 0; kst < 2; kst++)
                ax[kst] = *(const s16x8*)(smem + XHIo + swz(64 * wm + mf * 16 + ln, kst * 4 + g));
#pragma unroll
            for (int kst = 0; kst < 2; kst++)
#pragma unroll
                for (int nf = 0; nf < 4; nf++)
                    acc[mf][nf] = MFMA(ax[kst], bw[nf][kst], acc[mf][nf]);
        }
    }

    const int h = ((n0 + 64 * wn) >> 6) & 15;
#pragma unroll
    for (int nf = 0; nf < 4; nf++) {
        int e = nf * 16 + ln;
        float bvv = bv[h * 64 + e];
#pragma unroll
        for (int mf = 0; mf < 4; mf++) {
            int sgb = s0 + 64 * wm + mf * 16 + g * 4;   // 4 consecutive s
            int bidx = sgb >> 11, sr = sgb & (SS - 1);
            s16x4 v4;
#pragma unroll
            for (int r = 0; r < 4; r++) v4[r] = (short)f2bf(acc[mf][nf][r] + bvv);
            *(s16x4*)(VtG + ((size_t)((bidx * HH + h) * DHH + e)) * SS + sr) = v4;
        }
    }
}

// ---------------------------------------------------------------------------
// K3: attention. 64 q-rows/block (16 per wave), 1024 blocks -> 4 blocks/CU,
// 16 waves/CU. LDS 32KB. XCD-swizzled block mapping. Direct-global Q frags.
// Swapped QK^T (A=K,B=Q) -> S^T; full-row online stats; tril mask on P only.
// ---------------------------------------------------------------------------
__global__ __launch_bounds__(256, 4) void attn_kernel(
    const short* __restrict__ QhiG, const short* __restrict__ QloG,
    const short* __restrict__ KhiG, const short* __restrict__ KloG,
    const short* __restrict__ VtG,
    float* __restrict__ out)
{
    // XCD-aware bijective swizzle: 1024 blocks, 8 XCDs, 128 wids/XCD contiguous
    const int wid = (blockIdx.x & 7) * 128 + (blockIdx.x >> 3);
    const int qt = wid & 31, h = (wid >> 5) & 15, b = wid >> 9;
    const int q0 = qt * 64;
    const size_t ho = (size_t)(b * HH + h) * SS * DHH;   // same stride for Vt

    __shared__ __align__(16) char smem[32768];
    const int KHI = 0, KLO = 8192, VT = 16384, PS = 24576;

    const int t = threadIdx.x;
    const int w = t >> 6, lane = t & 63, g = lane >> 4, ln = lane & 15;
    const int qrow = 16 * w + ln;          // this lane's q-row (0..63)
    const int qg = q0 + qrow;              // global q index

    // Q fragments straight from global (read once)
    s16x8 qh[2], ql[2];
#pragma unroll
    for (int kst = 0; kst < 2; kst++) {
        size_t off = ho + (size_t)qg * DHH + kst * 32 + g * 8;
        qh[kst] = *(const s16x8*)(QhiG + off);
        ql[kst] = *(const s16x8*)(QloG + off);
    }

    f32x4 o[4];
#pragma unroll
    for (int i = 0; i < 4; i++) o[i] = (f32x4){0.f, 0.f, 0.f, 0.f};
    float m = -3.0e38f, l = 0.f;

    for (int kt = 0; kt < SS / 64; kt++) {
        const int k0 = kt * 64;
        const bool do_pv = (kt <= qt);
        __syncthreads();   // previous tile's reads of K/V done
#pragma unroll
        for (int p = 0; p < 2; p++) {
            int idx = p * 256 + t;
            int row = idx >> 3, blk = idx & 7;
            int soff = (blk ^ (row & 7)) * 8;
            glds16(KhiG + ho + (size_t)(k0 + row) * DHH + soff, smem + KHI + idx * 16);
            glds16(KloG + ho + (size_t)(k0 + row) * DHH + soff, smem + KLO + idx * 16);
            if (do_pv)
                glds16(VtG + ho + (size_t)row * SS + k0 + soff, smem + VT + idx * 16);
        }
        __syncthreads();

        // S^T tile: rows = k (64 across mf,g,r), cols = q (16 per wave)
        f32x4 s[4];
#pragma unroll
        for (int i = 0; i < 4; i++) s[i] = (f32x4){0.f, 0.f, 0.f, 0.f};

#pragma unroll
        for (int kst = 0; kst < 2; kst++) {
            s16x8 akh[4], akl[4];
#pragma unroll
            for (int mf = 0; mf < 4; mf++) {
                int off = swz(mf * 16 + ln, kst * 4 + g);
                akh[mf] = *(const s16x8*)(smem + KHI + off);
                akl[mf] = *(const s16x8*)(smem + KLO + off);
            }
#pragma unroll
            for (int mf = 0; mf < 4; mf++) {
                s[mf] = MFMA(akh[mf], qh[kst], s[mf]);
                s[mf] = MFMA(akh[mf], ql[kst], s[mf]);
                s[mf] = MFMA(akl[mf], qh[kst], s[mf]);
            }
        }

        // online softmax over FULL row (reference masks AFTER softmax).
        // defer-max (T13): skip O rescale when tile max grows <= 8.
        {
            float pm = s[0][0];
#pragma unroll
            for (int mf = 0; mf < 4; mf++)
#pragma unroll
                for (int r = 0; r < 4; r++) pm = fmaxf(pm, s[mf][r]);
            pm = fmaxf(pm, __shfl_xor(pm, 16));
            pm = fmaxf(pm, __shfl_xor(pm, 32));
            const bool defer = __all(pm - m <= 8.0f);
            float nm = defer ? m : fmaxf(m, pm);
            float ps = 0.f;
#pragma unroll
            for (int mf = 0; mf < 4; mf++)
#pragma unroll
                for (int r = 0; r < 4; r++) {
                    float pe = __expf(s[mf][r] - nm);
                    s[mf][r] = pe;
                    ps += pe;
                }
            ps += __shfl_xor(ps, 16);
            ps += __shfl_xor(ps, 32);
            if (defer) {
                l += ps;
            } else {
                float fac = __expf(m - nm);
                l = l * fac + ps;
                m = nm;
#pragma unroll
                for (int mf = 0; mf < 4; mf++)
#pragma unroll
                    for (int r = 0; r < 4; r++) o[mf][r] *= fac;
            }
        }

        if (do_pv) {
            // write masked P^T (bf16) to LDS, packed 4-per-b64, swizzled
#pragma unroll
            for (int mf = 0; mf < 4; mf++) {
                int kb = k0 + mf * 16 + g * 4;
                s16x4 pv;
#pragma unroll
                for (int r = 0; r < 4; r++) {
                    float pp = (kb + r > qg) ? 0.f : s[mf][r];
                    pv[r] = (short)f2bf(pp);
                }
                int byte = PS + qrow * 128 + ((((mf * 2 + (g >> 1)) ^ (qrow & 7))) << 4) + (g & 1) * 8;
                *(s16x4*)(smem + byte) = pv;
            }
            asm volatile("s_waitcnt lgkmcnt(0)" ::: "memory");
            __builtin_amdgcn_sched_barrier(0);
#pragma unroll
            for (int kst = 0; kst < 2; kst++) {
                s16x8 av[4], bp;
#pragma unroll
                for (int mf = 0; mf < 4; mf++)
                    av[mf] = *(const s16x8*)(smem + VT + swz(mf * 16 + ln, kst * 4 + g));
                bp = *(const s16x8*)(smem + PS + swz(qrow, kst * 4 + g));
#pragma unroll
                for (int mf = 0; mf < 4; mf++)
                    o[mf] = MFMA(av[mf], bp, o[mf]);
            }
        }
    }

    // epilogue: Z^T rows = e, cols = q -> out[b][q][h*64+e]
    {
        float inv = 1.0f / l;
        float* op = out + ((size_t)(b * SS + qg)) * (HH * DHH) + h * DHH;
#pragma unroll
        for (int mf = 0; mf < 4; mf++) {
            float4 vv = {o[mf][0] * inv, o[mf][1] * inv,
                         o[mf][2] * inv, o[mf][3] * inv};
            *(float4*)(op + mf * 16 + g * 4) = vv;
        }
    }
}

extern "C" void kernel_launch(void* const* d_in, const int* in_sizes, int n_in,
                              void* d_out, int out_size, void* d_ws, size_t ws_size,
                              hipStream_t stream) {
    const float* X  = (const float*)d_in[0];
    const float* Wq = (const float*)d_in[1];
    const float* Wk = (const float*)d_in[2];
    const float* Wv = (const float*)d_in[3];
    const float* bq = (const float*)d_in[4];
    const float* bk = (const float*)d_in[5];
    const float* bv = (const float*)d_in[6];
    float* out = (float*)d_out;

    char* wsb = (char*)d_ws;
    short* Wthi = (short*)(wsb + WTHI_OFF);
    short* Wtlo = (short*)(wsb + WTLO_OFF);
    short* Vt   = (short*)(wsb + VT_OFF);     // overlays Wtlo (sequential lifetime)
    short* Qhi  = (short*)(wsb + QHI_OFF);
    short* Qlo  = (short*)(wsb + QLO_OFF);
    short* Khi  = (short*)(wsb + KHI_OFF);
    short* Klo  = (short*)(wsb + KLO_OFF);

    wsplit_kernel<<<dim3(16, 48), 256, 0, stream>>>(Wq, Wk, Wv, Wthi, Wtlo);
    proj_qk_kernel<<<dim3(32, 16), 256, 0, stream>>>(X, Wthi, Wtlo, bq, bk,
                                                     Qhi, Qlo, Khi, Klo);
    proj_v_kernel<<<dim3(32, 8), 256, 0, stream>>>(X, Wthi, bv, Vt);
    attn_kernel<<<1024, 256, 0, stream>>>(Qhi, Qlo, Khi, Klo, Vt, out);
}